// Round 5
// baseline (164.160 us; speedup 1.0000x reference)
//
#include <hip/hip_runtime.h>
#include <stdint.h>

typedef __attribute__((ext_vector_type(8))) _Float16 half8;
typedef __attribute__((ext_vector_type(2))) _Float16 h2;
typedef __attribute__((ext_vector_type(4))) float f32x4;

#define NCHUNK 32     // 4096 t / 128 t per chunk (2 i-slices per chunk)

static __device__ __forceinline__ unsigned short f2h(float f) {
  return __builtin_bit_cast(unsigned short, (_Float16)f);
}
// async global->LDS, 16 B per lane; lds dest must be wave-uniform base
static __device__ __forceinline__ void gload16(const void* g, void* l) {
  __builtin_amdgcn_global_load_lds((const __attribute__((address_space(1))) void*)g,
                                   (__attribute__((address_space(3))) void*)l, 16, 0, 0);
}

// ---- phase 1 (fused): Bs[k,i,j] = sym(sum_w wgt[w]*mix[w,k,i,j]) -> f16.
// One block per k (grid 64, 1024 thr). Thread owns float4 #tid of the 64x64
// tile; w-sum accumulates in registers; symmetrize via 16 KB LDS exchange;
// single f16 rounding at the end (more accurate than the old 2-step path).
__global__ __launch_bounds__(1024) void prep_kernel(const float* __restrict__ mix,
                                                    const float* __restrict__ wgt,
                                                    unsigned short* __restrict__ Bp) {
  __shared__ float T[4096];
  const int k   = blockIdx.x;
  const int tid = threadIdx.x;
  const float4* m4 = (const float4*)mix + (size_t)k * 1024 + tid;
  float4 a = {0.f, 0.f, 0.f, 0.f};
#pragma unroll
  for (int w = 0; w < 32; ++w) {
    const float s = wgt[w];
    const float4 v = m4[(size_t)w * 65536];
    a.x += s * v.x; a.y += s * v.y; a.z += s * v.z; a.w += s * v.w;
  }
  *(float4*)(&T[tid * 4]) = a;
  __syncthreads();
  // thread's 4 elems: t = tid*4+e -> same i = t>>6, j = (tid&15)*4+e
  ushort4 r;
#pragma unroll
  for (int e = 0; e < 4; ++e) {
    const int t = tid * 4 + e, i = t >> 6, j = t & 63;
    float v;
    if (i < j)       v = T[t] + T[(j << 6) | i];
    else if (i == j) v = T[t];
    else             v = 0.f;
    ((unsigned short*)&r)[e] = f2h(v);
  }
  ((ushort4*)Bp)[k * 1024 + tid] = r;
}

// ---- phase 2: out[z][k] = sum_t V[z,t]*Bs[k,t], V generated in-register ----
// 512 threads (8 waves) = 4 z-groups (wz) x 2 k-halves (wk); block = 256 z.
// Wave tile: 64 z x 32 k (f=4 A-frags reuse each B read).
// T3+T5 schedule: each chunk = 2 phases (il). Per phase: issue LDS reads ->
// s_barrier -> lgkmcnt(0) -> setprio(1) -> MFMA cluster (inline A-gen) ->
// setprio(0) -> s_barrier. Depth-2 staging with counted vmcnt(2) once per
// chunk (stage gloads stay in flight across barriers). XOR-16B-unit swizzle
// (verified 0 bank conflicts). Upper-triangular Bs: c>=16 skip h=0 half.
__global__ __launch_bounds__(512, 4) void gemm_kernel(const float* __restrict__ X,
                                                      const unsigned short* __restrict__ Bp,
                                                      float* __restrict__ out) {
  __shared__ unsigned short ldsB[3][64 * 128];    // 3 x 16 KB = 48 KB
  __shared__ unsigned short sH[2][2][256];        // [buf][il][dword*2+half] 2 KB

  const int tid  = threadIdx.x;
  const int lane = tid & 63;
  const int wv   = tid >> 6;    // wave 0..7
  const int wz   = wv >> 1;     // z-group 0..3 -> z rows wz*64..+63
  const int wk   = wv & 1;      // k-half 0/1 -> k cols wk*32..+31
  const int m    = lane & 15;
  const int q    = lane >> 4;
  const int zblk = blockIdx.x * 256;

  // stage chunk ct into ldsB[bf]: 8 waves x 2 iters x 1 KB segments.
  // segment s = wv*2+it covers rows 4s..4s+3; lane writes 16 B at dest+lane*16
  // (row = 4s + lane/16, slot u' = lane&15); source unit u = u' ^ (row&15).
  auto stageB = [&](int ct, int bf) {
#pragma unroll
    for (int it = 0; it < 2; ++it) {
      const int seg = wv * 2 + it;
      const int row = seg * 4 + (lane >> 4);
      const int u   = (lane & 15) ^ (row & 15);
      gload16(Bp + (size_t)row * 4096 + ct * 128 + u * 8,
              &ldsB[bf][seg * 512]);
    }
  };

  // s-broadcast publish: dword d = wz*32+m*2+fd holds lo = x[wz*64+fd*32+m, i],
  // hi = x[wz*64+fd*32+16+m, i]. Writer tid (0..255): z_local = tid,
  // bits: wz=tid[7:6], fd=tid[5], hf=tid[4], m=tid[3:0].
  auto publishS = [&](int bf, float2 xp) {
    if (tid < 256) {
      const int d  = (tid >> 6) * 32 + (tid & 15) * 2 + ((tid >> 5) & 1);
      const int hf = (tid >> 4) & 1;
      sH[bf][0][d * 2 + hf] = f2h(xp.x);
      sH[bf][1][d * 2 + hf] = f2h(xp.y);
    }
  };

  // ---- prologue: B chunks 0,1 + s chunk 0 ----
  stageB(0, 0);
  stageB(1, 1);
  {
    float2 xp0 = {0.f, 0.f};
    if (tid < 256) xp0 = *(const float2*)(X + (size_t)(zblk + tid) * 64);
    publishS(0, xp0);
  }

  // ---- per-lane f16 j-cache: jh[f][h*4+e] = {x[z(f,m), h*32+q*8+2e], x[..,+1]} ----
  h2 jh[4][8];
  {
    const float4* X4g = (const float4*)X;
#pragma unroll
    for (int f = 0; f < 4; ++f) {
      const int zg = zblk + wz * 64 + f * 16 + m;
#pragma unroll
      for (int h = 0; h < 2; ++h) {
        const float4 a = X4g[zg * 16 + h * 8 + q * 2];
        const float4 b = X4g[zg * 16 + h * 8 + q * 2 + 1];
        jh[f][h * 4 + 0] = h2{(_Float16)a.x, (_Float16)a.y};
        jh[f][h * 4 + 1] = h2{(_Float16)a.z, (_Float16)a.w};
        jh[f][h * 4 + 2] = h2{(_Float16)b.x, (_Float16)b.y};
        jh[f][h * 4 + 3] = h2{(_Float16)b.z, (_Float16)b.w};
      }
    }
  }

  f32x4 acc[4][2];
#pragma unroll
  for (int f = 0; f < 4; ++f)
#pragma unroll
    for (int g = 0; g < 2; ++g) acc[f][g] = f32x4{0.f, 0.f, 0.f, 0.f};

  __syncthreads();   // one-time full drain: chunks 0,1 staged, sH[0] ready

  int bufc = 0;
  for (int c = 0; c < NCHUNK; ++c) {
    const int cn = (c + 1) & (NCHUNK - 1);
    // next s-broadcast load (oldest VMEM of this chunk; waves 0..3 only)
    float2 spre = {0.f, 0.f};
    if (tid < 256)
      spre = *(const float2*)(X + (size_t)(zblk + tid) * 64 + cn * 2);
    // async-stage chunk c+2 into the third buffer (in flight across barriers)
    int bs = bufc + 2; if (bs >= 3) bs -= 3;
    stageB((c + 2) & (NCHUNK - 1), bs);

    const unsigned short* Bl = &ldsB[bufc][0];
    const bool full = (c < 16);

#pragma unroll
    for (int il = 0; il < 2; ++il) {
      // ---- read region: sv + B fragments for this il (both h) ----
      const uint2 sv = *(const uint2*)(&sH[c & 1][il][wz * 64 + m * 4]);
      h2 s2f[4];
      s2f[0] = __builtin_bit_cast(h2, __builtin_amdgcn_perm(sv.x, sv.x, 0x01000100u));
      s2f[1] = __builtin_bit_cast(h2, __builtin_amdgcn_perm(sv.x, sv.x, 0x03020302u));
      s2f[2] = __builtin_bit_cast(h2, __builtin_amdgcn_perm(sv.y, sv.y, 0x01000100u));
      s2f[3] = __builtin_bit_cast(h2, __builtin_amdgcn_perm(sv.y, sv.y, 0x03020302u));
      const unsigned short* base = Bl + (wk * 32 + m) * 128;
      const int u0 = ((il << 3) + q) ^ m;        // h=0 swizzled 16B unit
      const int u1 = ((il << 3) + 4 + q) ^ m;    // h=1 swizzled 16B unit
      half8 bf[2][2];
      if (full) {
        bf[0][0] = *(const half8*)(const void*)(base + u0 * 8);            // k=wk*32+m
        bf[0][1] = *(const half8*)(const void*)(base + 16 * 128 + u0 * 8); // k=+16
      }
      bf[1][0] = *(const half8*)(const void*)(base + u1 * 8);
      bf[1][1] = *(const half8*)(const void*)(base + 16 * 128 + u1 * 8);
      __builtin_amdgcn_sched_barrier(0);

      // ---- phase barrier A ----
      __builtin_amdgcn_s_barrier();
      asm volatile("s_waitcnt lgkmcnt(0)" ::: "memory");
      __builtin_amdgcn_sched_barrier(0);

      // ---- MFMA cluster (inline A-gen on the VALU pipe) ----
      __builtin_amdgcn_s_setprio(1);
      auto cluster = [&](int h, half8 b0, half8 b1) {
#pragma unroll
        for (int f = 0; f < 4; ++f) {
          union { unsigned u[4]; half8 v; } A;
#pragma unroll
          for (int e = 0; e < 4; ++e) {
            const h2 pr = s2f[f] * jh[f][h * 4 + e];   // v_pk_mul_f16 -> packed A
            A.u[e] = __builtin_bit_cast(unsigned, pr);
          }
          acc[f][0] = __builtin_amdgcn_mfma_f32_16x16x32_f16(A.v, b0, acc[f][0], 0, 0, 0);
          acc[f][1] = __builtin_amdgcn_mfma_f32_16x16x32_f16(A.v, b1, acc[f][1], 0, 0, 0);
        }
      };
      if (full) cluster(0, bf[0][0], bf[0][1]);  // j<32 half only while i<32
      cluster(1, bf[1][0], bf[1][1]);
      __builtin_amdgcn_s_setprio(0);

      if (il == 1) {
        // end of chunk: publish next s-broadcast, counted waits.
        // vmcnt(2): chunk c+1's stage (2 oldest gloads) done; chunk c+2's 2
        // newest stay in flight ACROSS the barrier. lgkmcnt(0): sH writes
        // visible to all waves after the barrier.
        publishS(cn & 1, spre);
        asm volatile("s_waitcnt vmcnt(2)" ::: "memory");
        asm volatile("s_waitcnt lgkmcnt(0)" ::: "memory");
      }
      // ---- phase barrier B ----
      __builtin_amdgcn_s_barrier();
      __builtin_amdgcn_sched_barrier(0);
    }
    bufc = (bufc + 1 == 3) ? 0 : bufc + 1;
  }

  // ---- epilogue: C/D layout col=lane&15 (k), row=q*4+r (z) ----
#pragma unroll
  for (int f = 0; f < 4; ++f) {
    const int zr = zblk + wz * 64 + f * 16 + q * 4;
#pragma unroll
    for (int g = 0; g < 2; ++g)
#pragma unroll
      for (int r = 0; r < 4; ++r)
        out[(size_t)(zr + r) * 64 + wk * 32 + g * 16 + m] = acc[f][g][r];
  }
}

extern "C" void kernel_launch(void* const* d_in, const int* in_sizes, int n_in,
                              void* d_out, int out_size, void* d_ws, size_t ws_size,
                              hipStream_t stream) {
  const float* X   = (const float*)d_in[0];   // [131072, 64]
  const float* mix = (const float*)d_in[1];   // [32, 64, 64, 64]
  const float* wgt = (const float*)d_in[2];   // [32]
  float* out = (float*)d_out;                 // [131072, 64]
  unsigned short* Bp = (unsigned short*)d_ws; // 512 KB scratch: Bs f16 [64][4096]

  prep_kernel<<<64, 1024, 0, stream>>>(mix, wgt, Bp);
  gemm_kernel<<<512, 512, 0, stream>>>(X, Bp, out);
}

// Round 8
// 158.577 us; speedup vs baseline: 1.0352x; 1.0352x over previous
//
#include <hip/hip_runtime.h>
#include <stdint.h>

typedef __attribute__((ext_vector_type(8))) _Float16 half8;
typedef __attribute__((ext_vector_type(2))) _Float16 h2;
typedef __attribute__((ext_vector_type(4))) float f32x4;

static __device__ __forceinline__ unsigned short f2h(float f) {
  return __builtin_bit_cast(unsigned short, (_Float16)f);
}

// ---- phase 1 (fused): Bs = sym(sum_w wgt[w]*mix[w]) -> f16, FRAGMENT-MAJOR.
// Bs[k][t] lives at short offset ((t>>5)*4 + (k>>4))*512 + ((t>>3)&3)*128
//   + (k&15)*8 + (t&7). A wave-wide uint4 load at element index
//   (((c*4+il*2+h)*4+g)*64 + lane) is then fully coalesced (1 KB/instr) and
//   hands lane (m=lane&15, q=lane>>4) exactly B[k=g*16+m][t=c*128+il*64+h*32+q*8..+7].
__global__ __launch_bounds__(1024) void prep_kernel(const float* __restrict__ mix,
                                                    const float* __restrict__ wgt,
                                                    unsigned short* __restrict__ Bp) {
  __shared__ float T[4096];
  const int k   = blockIdx.x;
  const int tid = threadIdx.x;
  const float4* m4 = (const float4*)mix + (size_t)k * 1024 + tid;
  float4 a = {0.f, 0.f, 0.f, 0.f};
#pragma unroll
  for (int w = 0; w < 32; ++w) {
    const float s = wgt[w];
    const float4 v = m4[(size_t)w * 65536];
    a.x += s * v.x; a.y += s * v.y; a.z += s * v.z; a.w += s * v.w;
  }
  *(float4*)(&T[tid * 4]) = a;
  __syncthreads();
  // Bs[i,j] = M[i,j]+M[j,i] (i<j), M[i,i] (i==j), 0 (i>j)  -- verified r2-r5
  ushort4 r;
#pragma unroll
  for (int e = 0; e < 4; ++e) {
    const int t = tid * 4 + e, i = t >> 6, j = t & 63;
    float v;
    if (i < j)       v = T[t] + T[(j << 6) | i];
    else if (i == j) v = T[t];
    else             v = 0.f;
    ((unsigned short*)&r)[e] = f2h(v);
  }
  const int t0  = tid * 4;
  const int off = ((t0 >> 5) * 4 + (k >> 4)) * 512 + ((t0 >> 3) & 3) * 128
                + (k & 15) * 8 + (t0 & 7);
  *(ushort4*)(Bp + off) = r;   // 8B-aligned: (k&15)*8 + {0,4}
}

// static schedule of (c, il, h) compute blocks: 16 full chunks x 4 + 16 skip x 2
static __device__ __forceinline__ void blk_coords(int idx, int& c, int& il, int& h) {
  if (idx < 64) { c = idx >> 2; il = (idx >> 1) & 1; h = idx & 1; }
  else { const int r = idx - 64; c = 16 + (r >> 1); il = r & 1; h = 1; }
}

// ---- phase 2: out[z][k] = sum_t V[z,t]*Bs[k,t], V generated in-register ----
// BARRIER-FREE, ZERO-LDS. 256 threads (4 waves); wave owns 32 z (f=2);
// block = 128 z; grid 1024. B fragments stream from global (L1/L2-resident
// 512 KB, shared by all blocks -- common-mistake #7: don't LDS-stage L2-fit
// data) via fully-coalesced dwordx4 reads of the fragment-major layout,
// depth-2 register prefetch (3-slot rotation, all indices static).
// s = x[z, i=2c+il] extracted from the register j-cache via one __shfl from
// lane q_s*16+m (same z) + v_perm f16 splat. Math identical to verified r2-r5:
// dense t, upper-triangular h=0 skip for c>=16, 16x16x32 f16 MFMA,
// round-3 A-gen, round-2 epilogue.
__global__ __launch_bounds__(256, 3) void gemm_kernel(const float* __restrict__ X,
                                                      const unsigned short* __restrict__ Bp,
                                                      float* __restrict__ out) {
  const int tid  = threadIdx.x;
  const int lane = tid & 63;
  const int wv   = tid >> 6;    // wave 0..3 -> z rows wv*32..+31
  const int m    = lane & 15;
  const int q    = lane >> 4;
  const int zblk = blockIdx.x * 128;

  // ---- per-lane f16 j-cache: jh[f][h*4+e] = {x[z(f,m), h*32+q*8+2e], x[..,+1]} ----
  h2 jh[2][8];
  {
    const float4* X4g = (const float4*)X;
#pragma unroll
    for (int f = 0; f < 2; ++f) {
      const int zg = zblk + wv * 32 + f * 16 + m;
#pragma unroll
      for (int h = 0; h < 2; ++h) {
        const float4 a = X4g[zg * 16 + h * 8 + q * 2];
        const float4 b = X4g[zg * 16 + h * 8 + q * 2 + 1];
        jh[f][h * 4 + 0] = h2{(_Float16)a.x, (_Float16)a.y};
        jh[f][h * 4 + 1] = h2{(_Float16)a.z, (_Float16)a.w};
        jh[f][h * 4 + 2] = h2{(_Float16)b.x, (_Float16)b.y};
        jh[f][h * 4 + 3] = h2{(_Float16)b.z, (_Float16)b.w};
      }
    }
  }

  f32x4 acc[2][4];
#pragma unroll
  for (int f = 0; f < 2; ++f)
#pragma unroll
    for (int g = 0; g < 4; ++g) acc[f][g] = f32x4{0.f, 0.f, 0.f, 0.f};

  const uint4* Bv = (const uint4*)Bp;
  uint4 bbuf[3][4];
  auto loadB = [&](int idx, uint4* dst) {
    int c, il, h; blk_coords(idx, c, il, h);
    const int s4 = (c * 4 + il * 2 + h) * 4;
#pragma unroll
    for (int g = 0; g < 4; ++g) dst[g] = Bv[(s4 + g) * 64 + lane];
  };

  loadB(0, bbuf[0]);
  loadB(1, bbuf[1]);

#pragma unroll
  for (int idx = 0; idx < 96; ++idx) {
    if (idx + 2 < 96) loadB(idx + 2, bbuf[(idx + 2) % 3]);

    int c, il, h; blk_coords(idx, c, il, h);
    // ---- s = x[z, i] via shfl from the lane holding that j-slice ----
    const int i    = 2 * c + il;
    const int hs   = i >> 5;          // static after unroll
    const int qs   = (i >> 3) & 3;
    const int es   = (i & 7) >> 1;
    const int half = i & 1;
    h2 s2f[2];
#pragma unroll
    for (int f = 0; f < 2; ++f) {
      const int du = __shfl((int)__builtin_bit_cast(unsigned, jh[f][hs * 4 + es]),
                            qs * 16 + m, 64);
      const unsigned uu = (unsigned)du;
      s2f[f] = __builtin_bit_cast(h2, __builtin_amdgcn_perm(uu, uu,
                                   half ? 0x03020302u : 0x01000100u));
    }

    // ---- compute: A-gen (v_pk_mul_f16) + 8 MFMA on bbuf[idx%3] ----
    const uint4* bc = bbuf[idx % 3];
#pragma unroll
    for (int f = 0; f < 2; ++f) {
      union { unsigned u[4]; half8 v; } A;
#pragma unroll
      for (int e = 0; e < 4; ++e) {
        const h2 pr = s2f[f] * jh[f][h * 4 + e];
        A.u[e] = __builtin_bit_cast(unsigned, pr);
      }
#pragma unroll
      for (int g = 0; g < 4; ++g)
        acc[f][g] = __builtin_amdgcn_mfma_f32_16x16x32_f16(
            A.v, __builtin_bit_cast(half8, bc[g]), acc[f][g], 0, 0, 0);
    }
  }

  // ---- epilogue: C/D layout col=lane&15 (k), row=q*4+r (z) ----
#pragma unroll
  for (int f = 0; f < 2; ++f) {
    const int zr = zblk + wv * 32 + f * 16 + q * 4;
#pragma unroll
    for (int g = 0; g < 4; ++g)
#pragma unroll
      for (int r = 0; r < 4; ++r)
        out[(size_t)(zr + r) * 64 + g * 16 + m] = acc[f][g][r];
  }
}

extern "C" void kernel_launch(void* const* d_in, const int* in_sizes, int n_in,
                              void* d_out, int out_size, void* d_ws, size_t ws_size,
                              hipStream_t stream) {
  const float* X   = (const float*)d_in[0];   // [131072, 64]
  const float* mix = (const float*)d_in[1];   // [32, 64, 64, 64]
  const float* wgt = (const float*)d_in[2];   // [32]
  float* out = (float*)d_out;                 // [131072, 64]
  unsigned short* Bp = (unsigned short*)d_ws; // 512 KB: Bs f16, fragment-major

  prep_kernel<<<64, 1024, 0, stream>>>(mix, wgt, Bp);
  gemm_kernel<<<1024, 256, 0, stream>>>(X, Bp, out);
}

// Round 9
// 148.476 us; speedup vs baseline: 1.1056x; 1.0680x over previous
//
#include <hip/hip_runtime.h>
#include <stdint.h>

typedef __attribute__((ext_vector_type(8))) _Float16 half8;
typedef __attribute__((ext_vector_type(2))) _Float16 h2;
typedef __attribute__((ext_vector_type(4))) float f32x4;

static __device__ __forceinline__ unsigned short f2h(float f) {
  return __builtin_bit_cast(unsigned short, (_Float16)f);
}
// async global->LDS, 16 B per lane; lds dest must be wave-uniform base
static __device__ __forceinline__ void gload16(const void* g, void* l) {
  __builtin_amdgcn_global_load_lds((const __attribute__((address_space(1))) void*)g,
                                   (__attribute__((address_space(3))) void*)l, 16, 0, 0);
}

// ---- phase 1 (fused, verified r5): Bs = sym(sum_w wgt[w]*mix[w]) -> f16 [64][4096] ----
__global__ __launch_bounds__(1024) void prep_kernel(const float* __restrict__ mix,
                                                    const float* __restrict__ wgt,
                                                    unsigned short* __restrict__ Bp) {
  __shared__ float T[4096];
  const int k   = blockIdx.x;
  const int tid = threadIdx.x;
  const float4* m4 = (const float4*)mix + (size_t)k * 1024 + tid;
  float4 a = {0.f, 0.f, 0.f, 0.f};
#pragma unroll
  for (int w = 0; w < 32; ++w) {
    const float s = wgt[w];
    const float4 v = m4[(size_t)w * 65536];
    a.x += s * v.x; a.y += s * v.y; a.z += s * v.z; a.w += s * v.w;
  }
  *(float4*)(&T[tid * 4]) = a;
  __syncthreads();
  ushort4 r;
#pragma unroll
  for (int e = 0; e < 4; ++e) {
    const int t = tid * 4 + e, i = t >> 6, j = t & 63;
    float v;
    if (i < j)       v = T[t] + T[(j << 6) | i];
    else if (i == j) v = T[t];
    else             v = 0.f;
    ((unsigned short*)&r)[e] = f2h(v);
  }
  ((ushort4*)Bp)[k * 1024 + tid] = r;
}

// ---- phase 2: out[z][k] = sum_t V[z,t]*Bs[k,t] ----
// ZERO BARRIERS. 256 threads = 4 waves = 2 z-groups (wzg) x 2 k-halves (wk);
// wave tile = 128 z x 32 k (f=8, g=2). Each wave owns a PRIVATE 2x8KB LDS
// double-buffer and DMA-stages its own B k-slice chunk-by-chunk; sync is
// wave-local s_waitcnt vmcnt(8) only (depth-2: chunk c+2 in flight while
// computing c). L2 B-traffic = 2048 waves x 256 KB = 524 MB (vs r8's 1.57 GB).
// Verified components: r2-5 XOR-16B-unit swizzle (0 conflicts) + stage
// pattern, r8 shfl-based s extraction, r3 A-gen, r2 epilogue, h=0 skip c>=16.
// Loop nesting hs(2,unroll) x qs(4,runtime) x es(4,unroll): c = hs*16+qs*4+es
// iterates 0..31 in order; all jh[] indices compile-time (rule #20) while
// code stays ~8 bodies (< L1I). Wrap-around junk stages keep vmcnt(8) uniform.
__global__ __launch_bounds__(256, 2) void gemm_kernel(const float* __restrict__ X,
                                                      const unsigned short* __restrict__ Bp,
                                                      float* __restrict__ out) {
  __shared__ unsigned short ldsB[4][2][4096];   // [wave][dbuf][32k x 128t]  64 KB

  const int tid  = threadIdx.x;
  const int lane = tid & 63;
  const int wv   = tid >> 6;    // wave 0..3
  const int wzg  = wv >> 1;     // z-group 0/1 -> z rows wzg*128..+127
  const int wk   = wv & 1;      // k-half 0/1 -> k cols wk*32..+31
  const int m    = lane & 15;
  const int q    = lane >> 4;
  const int zblk = blockIdx.x * 256;

  // ---- per-lane f16 j-cache: jh[f][h*4+e] = {x[z(f,m), h*32+q*8+2e], x[..,+1]} ----
  h2 jh[8][8];
  {
    const float4* X4g = (const float4*)X;
#pragma unroll
    for (int f = 0; f < 8; ++f) {
      const int zg = zblk + wzg * 128 + f * 16 + m;
#pragma unroll
      for (int h = 0; h < 2; ++h) {
        const float4 a = X4g[zg * 16 + h * 8 + q * 2];
        const float4 b = X4g[zg * 16 + h * 8 + q * 2 + 1];
        jh[f][h * 4 + 0] = h2{(_Float16)a.x, (_Float16)a.y};
        jh[f][h * 4 + 1] = h2{(_Float16)a.z, (_Float16)a.w};
        jh[f][h * 4 + 2] = h2{(_Float16)b.x, (_Float16)b.y};
        jh[f][h * 4 + 3] = h2{(_Float16)b.z, (_Float16)b.w};
      }
    }
  }

  f32x4 acc[8][2];
#pragma unroll
  for (int f = 0; f < 8; ++f) {
    acc[f][0] = f32x4{0.f, 0.f, 0.f, 0.f};
    acc[f][1] = f32x4{0.f, 0.f, 0.f, 0.f};
  }

  // drain X loads: from here on, the only in-flight VMEM are stage DMAs,
  // making the loop's vmcnt counting exact.
  asm volatile("s_waitcnt vmcnt(0)" ::: "memory");

  const unsigned short* gB = Bp + (size_t)(wk * 32) * 4096;  // wave's k-slice
  unsigned short* myB = &ldsB[wv][0][0];                     // wave-private LDS

  // stage chunk ct (8 KB = 8 x 1KB segs) into private buf bf; linear dest,
  // inverse-swizzled source unit u = (lane&15) ^ (row&15)  [verified r2-r5]
  auto stageB = [&](int ct, int bf) {
#pragma unroll
    for (int s = 0; s < 8; ++s) {
      const int row = s * 4 + (lane >> 4);
      const int u   = (lane & 15) ^ (row & 15);
      gload16(gB + (size_t)row * 4096 + ct * 128 + u * 8,
              myB + bf * 4096 + s * 512);
    }
  };

  stageB(0, 0);
  stageB(1, 1);

#pragma unroll
  for (int hs = 0; hs < 2; ++hs) {
#pragma unroll 1
    for (int qs = 0; qs < 4; ++qs) {     // runtime loop: keeps code < L1I
#pragma unroll
      for (int es = 0; es < 4; ++es) {
        const int c = hs * 16 + qs * 4 + es;   // chunks iterate 0..31 in order
        // chunk c's DMA complete; 8 newest (chunk c+1) stay in flight
        asm volatile("s_waitcnt vmcnt(8)" ::: "memory");

        const unsigned short* Bl = myB + (es & 1) * 4096;
#pragma unroll
        for (int il = 0; il < 2; ++il) {
          // s = x[z(f,m), i], i = 2c+il: shfl from lane qs*16+m (verified r8)
          h2 s2f[8];
#pragma unroll
          for (int f = 0; f < 8; ++f) {
            const int du = __shfl((int)__builtin_bit_cast(unsigned, jh[f][hs * 4 + es]),
                                  qs * 16 + m, 64);
            const unsigned uu = (unsigned)du;
            s2f[f] = __builtin_bit_cast(h2, __builtin_amdgcn_perm(uu, uu,
                                     il ? 0x03020302u : 0x01000100u));
          }
#pragma unroll
          for (int h = 0; h < 2; ++h) {
            if (hs == 1 && h == 0) continue;   // upper-triangular skip (exact)
            const int sb = il * 2 + h;
            const int u  = (sb * 4 + q) ^ m;   // swizzled 16B unit
            const unsigned short* bb = Bl + m * 128 + u * 8;
            const half8 b0 = *(const half8*)(const void*)(bb);            // k=wk*32+m
            const half8 b1 = *(const half8*)(const void*)(bb + 16 * 128); // k=+16
#pragma unroll
            for (int f = 0; f < 8; ++f) {
              union { unsigned u[4]; half8 v; } A;
#pragma unroll
              for (int e = 0; e < 4; ++e) {
                const h2 pr = s2f[f] * jh[f][h * 4 + e];   // v_pk_mul_f16
                A.u[e] = __builtin_bit_cast(unsigned, pr);
              }
              acc[f][0] = __builtin_amdgcn_mfma_f32_16x16x32_f16(A.v, b0, acc[f][0], 0, 0, 0);
              acc[f][1] = __builtin_amdgcn_mfma_f32_16x16x32_f16(A.v, b1, acc[f][1], 0, 0, 0);
            }
          }
        }
        // all of chunk c's ds_reads complete -> safe to DMA-overwrite buf c&1
        asm volatile("s_waitcnt lgkmcnt(0)" ::: "memory");
        stageB((c + 2) & 31, es & 1);   // wraps to junk re-stage at c=30,31
      }
    }
  }

  // ---- epilogue: C/D layout col=lane&15 (k), row=q*4+r (z)  [verified r2] ----
#pragma unroll
  for (int f = 0; f < 8; ++f) {
    const int zr = zblk + wzg * 128 + f * 16 + q * 4;
#pragma unroll
    for (int g = 0; g < 2; ++g)
#pragma unroll
      for (int r = 0; r < 4; ++r)
        out[(size_t)(zr + r) * 64 + wk * 32 + g * 16 + m] = acc[f][g][r];
  }
}

extern "C" void kernel_launch(void* const* d_in, const int* in_sizes, int n_in,
                              void* d_out, int out_size, void* d_ws, size_t ws_size,
                              hipStream_t stream) {
  const float* X   = (const float*)d_in[0];   // [131072, 64]
  const float* mix = (const float*)d_in[1];   // [32, 64, 64, 64]
  const float* wgt = (const float*)d_in[2];   // [32]
  float* out = (float*)d_out;                 // [131072, 64]
  unsigned short* Bp = (unsigned short*)d_ws; // 512 KB: Bs f16 [64][4096]

  prep_kernel<<<64, 1024, 0, stream>>>(mix, wgt, Bp);
  gemm_kernel<<<512, 256, 0, stream>>>(X, Bp, out);
}